// Round 17
// baseline (218.312 us; speedup 1.0000x reference)
//
#include <hip/hip_runtime.h>
#include <cmath>
#include <cstdint>

// Problem constants (fixed by reference file)
#define B_     8
#define NH_    32
#define HD_    128
#define HID_   4096
#define MAXS_  4096
#define NPAIR_ (B_ * NH_)          // 256 (b,h) pairs
#define QS_    (3 * B_ * HID_)     // qkv partial stride (one K-half)
#define NEG_BIG_ (-1e30f)

typedef float f4_ __attribute__((ext_vector_type(4)));

__device__ __forceinline__ f4_ ntload4(const float* p) {
  return __builtin_nontemporal_load((const f4_*)p);
}
__device__ __forceinline__ f4_ ld4(const float* p) {
  return *(const f4_*)p;
}
__device__ __forceinline__ float dot4(f4_ a, f4_ b) {
  f4_ m = a * b;
  return m.x + m.y + m.z + m.w;
}

// Async global->LDS stage of 16 B/lane (1 KB per wave-instruction).
// Per-lane global src; LDS dest = wave-uniform byte offset + lane*16.
// Dynamic-LDS raw offsets (no static __shared__). Verified in round 9.
__device__ __forceinline__ void stage16(const float* gsrc, unsigned ldsoff) {
  __builtin_amdgcn_global_load_lds(
      (__attribute__((address_space(1))) void*)(uintptr_t)gsrc,
      (__attribute__((address_space(3))) void*)ldsoff,
      16, 0, 0);
}

// Pure-weight-stream GEMV, high-TLP variant: 8-wave (512 thr) block, 32 rows
// (4/wave), NSL K-slices of 256. Whole x K-range staged to LDS up front (one
// barrier); stream loop = reg-double-buffered weight loads + ds_read x + FMA
// only. Round-16 isolation showed the loop is now weight-latency-limited at
// 2 waves/SIMD (~180 VGPR); 4 rows/wave + __launch_bounds__(512,4) caps VGPR
// at 128 -> 4 waves/SIMD (16 waves/CU), doubling latency-hiding TLP on the
// weight stream. Weights NORMAL loads (L3-resident across graph replays; the
// nt KV stream can't evict them — round-5/6 A/B).
template<int NSL>
__global__ __launch_bounds__(512, 4) void gemv_xlds(
    const float* __restrict__ W0, const float* __restrict__ W1,
    const float* __restrict__ W2, const float* __restrict__ x,
    float* __restrict__ out, int nb_per_mat, int n_inner, int part_stride)
{
  extern __shared__ float dyn[];            // [8][NSL][256] floats
  const int bid   = blockIdx.x;
  const int ks    = bid / n_inner;          // K-split index
  const int inner = bid % n_inner;
  const int m     = inner / nb_per_mat;     // matrix index (0..2)
  const int r0    = (inner % nb_per_mat) * 32;
  const float* __restrict__ W = (m == 0) ? W0 : ((m == 1) ? W1 : W2);
  float* o = out + (size_t)ks * part_stride + m * (B_ * HID_);

  const int wib  = threadIdx.x >> 6;        // 0..7
  const int lane = threadIdx.x & 63;
  const int kofs = ks * NSL * 256;
  const int rw   = r0 + wib * 4;            // wave's first row (4 rows/wave)

  float acc[4][8];
#pragma unroll
  for (int r = 0; r < 4; ++r)
#pragma unroll
    for (int b = 0; b < 8; ++b) acc[r][b] = 0.f;

  const float* Wp = W + (size_t)rw * HID_ + kofs + lane * 4;
  const float* xp = x + kofs + lane * 4;

  // stage the whole x K-range: wave wib stages batch b = wib
  {
    const int b = wib;
#pragma unroll
    for (int s = 0; s < NSL; ++s)
      stage16(xp + (size_t)b * HID_ + s * 256,
              (unsigned)((b * NSL + s) * 1024));
  }

  f4_ wa[4], wb[4];
#pragma unroll
  for (int r = 0; r < 4; ++r) wa[r] = ld4(Wp + (size_t)r * HID_);
  __syncthreads();                          // one-time drain; staging done

#define COMP_(BUF, u)                                                         \
  {                                                                           \
    f4_ xv[8];                                                                \
    _Pragma("unroll")                                                         \
    for (int b = 0; b < 8; ++b)                                               \
      xv[b] = ld4(&dyn[(b * NSL + (u)) * 256 + lane * 4]);                    \
    _Pragma("unroll")                                                         \
    for (int r = 0; r < 4; ++r)                                               \
      _Pragma("unroll")                                                       \
      for (int b = 0; b < 8; ++b) acc[r][b] += dot4(BUF[r], xv[b]);           \
  }

#pragma unroll 1
  for (int u = 0; u < NSL; u += 2) {
    {
#pragma unroll
      for (int r = 0; r < 4; ++r)
        wb[r] = ld4(Wp + (size_t)r * HID_ + (u + 1) * 256);
      COMP_(wa, u);
    }
    {
      if (u + 2 < NSL) {
#pragma unroll
        for (int r = 0; r < 4; ++r)
          wa[r] = ld4(Wp + (size_t)r * HID_ + (u + 2) * 256);
      }
      COMP_(wb, u + 1);
    }
  }
#undef COMP_

  // butterfly reduce each of the 32 partials across the wave
#pragma unroll
  for (int r = 0; r < 4; ++r)
#pragma unroll
    for (int b = 0; b < 8; ++b) {
      float v = acc[r][b];
#pragma unroll
      for (int off = 32; off; off >>= 1) v += __shfl_xor(v, off);
      acc[r][b] = v;
    }

  if (lane == 0) {
#pragma unroll
    for (int r = 0; r < 4; ++r)
#pragma unroll
      for (int b = 0; b < 8; ++b)
        o[(size_t)b * HID_ + rw + r] = acc[r][b];
  }
}

// out[i] = sum of 4 K-split partials (deterministic, no atomics).
__global__ __launch_bounds__(256) void sum4(
    const float* __restrict__ part, float* __restrict__ out)
{
  const int gid = blockIdx.x * 256 + threadIdx.x;   // 8192 f4 elements
  const int i = gid * 4;
  f4_ v = ld4(part + i) + ld4(part + (B_ * HID_) + i)
        + ld4(part + 2 * (B_ * HID_) + i) + ld4(part + 3 * (B_ * HID_) + i);
  *(f4_*)(out + i) = v;
}

// Fused flash-decoding attention: ONE block (512 thr = 8 waves) per (b,h),
// combine in-block. q/k/v-fresh are the SUM of the two QKV K-split halves.
// K/V rows nt (stream-once; must not evict L3-resident weights).
__global__ __launch_bounds__(512) void attn_pair(
    const float* __restrict__ qkv, const float* __restrict__ ck,
    const float* __restrict__ cv, const int* __restrict__ ppos,
    float* __restrict__ attnout)
{
  __shared__ float sm[8], sl[8];
  __shared__ float sacc[8][HD_];

  const int pos  = *ppos;
  const int pair = blockIdx.x;
  const int b    = pair >> 5;
  const int h    = pair & (NH_ - 1);
  const int w    = threadIdx.x >> 6;
  const int lane = threadIdx.x & 63;
  const int half = lane >> 5, l32 = lane & 31;
  const int k0   = w * 256;

  float m = NEG_BIG_, l = 0.f;
  f4_ acc = (f4_)0.f;

  if (k0 <= pos) {
    const float scale = 0.08838834764831845f;   // 1/sqrt(128)
    const int hoff = b * HID_ + h * HD_ + l32 * 4;
    f4_ q4  = (ld4(qkv + hoff) + ld4(qkv + QS_ + hoff)) * scale;
    f4_ kf4 =  ld4(qkv + B_ * HID_ + hoff) + ld4(qkv + QS_ + B_ * HID_ + hoff);
    f4_ vf4 =  ld4(qkv + 2 * B_ * HID_ + hoff) + ld4(qkv + QS_ + 2 * B_ * HID_ + hoff);
    const float* ckh = ck + ((size_t)(b * NH_ + h)) * MAXS_ * HD_;
    const float* cvh = cv + ((size_t)(b * NH_ + h)) * MAXS_ * HD_;

    for (int c = 0; c < 16; ++c) {
      const int kbase = k0 + c * 16;
      f4_ k4[8], v4[8];
#pragma unroll
      for (int j = 0; j < 8; ++j) {
        const int ki = kbase + 2 * j + half;
        k4[j] = ntload4(ckh + (size_t)ki * HD_ + l32 * 4);
        v4[j] = ntload4(cvh + (size_t)ki * HD_ + l32 * 4);
      }
      // fresh-token overwrite (ki==pos row of the cache is stale)
#pragma unroll
      for (int j = 0; j < 8; ++j) {
        const int ki = kbase + 2 * j + half;
        if (ki == pos) { k4[j] = kf4; v4[j] = vf4; }
      }

      float sc[8];
#pragma unroll
      for (int j = 0; j < 8; ++j) sc[j] = dot4(q4, k4[j]);

#pragma unroll
      for (int off = 16; off >= 1; off >>= 1)
#pragma unroll
        for (int j = 0; j < 8; ++j) sc[j] += __shfl_xor(sc[j], off);

#pragma unroll
      for (int j = 0; j < 8; ++j) {
        const int ki = kbase + 2 * j + half;
        if (ki > pos) sc[j] = -INFINITY;
      }

      const float cm = fmaxf(fmaxf(fmaxf(sc[0], sc[1]), fmaxf(sc[2], sc[3])),
                             fmaxf(fmaxf(sc[4], sc[5]), fmaxf(sc[6], sc[7])));
      const float mn   = fmaxf(m, cm);
      const float corr = __expf(m - mn);
      float p[8], ps = 0.f;
#pragma unroll
      for (int j = 0; j < 8; ++j) { p[j] = __expf(sc[j] - mn); ps += p[j]; }
      l = l * corr + ps;
      acc *= corr;
#pragma unroll
      for (int j = 0; j < 8; ++j) acc += p[j] * v4[j];
      m = mn;
    }
  }

  // merge the two halves of each wave
  const float mo = __shfl_xor(m, 32);
  const float lo = __shfl_xor(l, 32);
  f4_ ao;
  ao.x = __shfl_xor(acc.x, 32); ao.y = __shfl_xor(acc.y, 32);
  ao.z = __shfl_xor(acc.z, 32); ao.w = __shfl_xor(acc.w, 32);
  const float mm = fmaxf(m, mo);
  const float w0 = __expf(m - mm), w1 = __expf(mo - mm);
  const float lm = l * w0 + lo * w1;
  f4_ am = acc * w0 + ao * w1;

  if (half == 0) {
    *(f4_*)&sacc[w][l32 * 4] = am;
    if (l32 == 0) { sm[w] = mm; sl[w] = lm; }
  }
  __syncthreads();

  // final merge of the 8 wave-partials (32 threads, one f4 per thread)
  if (threadIdx.x < 32) {
    const int t = threadIdx.x;
    float mg = NEG_BIG_;
#pragma unroll
    for (int u = 0; u < 8; ++u)
      if (sl[u] > 0.f) mg = fmaxf(mg, sm[u]);
    float ls = 0.f;
    f4_ o = (f4_)0.f;
#pragma unroll
    for (int u = 0; u < 8; ++u)
      if (sl[u] > 0.f) {
        const float wu = __expf(sm[u] - mg);
        ls += sl[u] * wu;
        o  += wu * ld4(&sacc[u][t * 4]);
      }
    *(f4_*)(attnout + pair * HD_ + t * 4) = o / ls;
  }
}

extern "C" void kernel_launch(void* const* d_in, const int* in_sizes, int n_in,
                              void* d_out, int out_size, void* d_ws, size_t ws_size,
                              hipStream_t stream) {
  const float* x  = (const float*)d_in[0];
  const float* ck = (const float*)d_in[1];
  const float* cv = (const float*)d_in[2];
  const float* wq = (const float*)d_in[3];
  const float* wk = (const float*)d_in[4];
  const float* wv = (const float*)d_in[5];
  const float* wo = (const float*)d_in[6];
  const int* pos  = (const int*)d_in[7];
  float* out = (float*)d_out;
  float* ws  = (float*)d_ws;

  float* qkvp    = ws;                                   // 2 * QS_ floats
  float* attnout = qkvp + 2 * QS_;                       // B*HID
  float* wopart  = attnout + B_ * HID_;                  // 4 * B*HID

  // QKV: K-split x2, 32-row 8-wave blocks, whole-x-in-LDS (64 KB each)
  gemv_xlds<8><<<2 * 3 * 128, 512, 65536, stream>>>(wq, wk, wv, x, qkvp,
                                                    128, 3 * 128, QS_);
  // attention + combine fused (sums the two qkv K-halves on load)
  attn_pair<<<NPAIR_, 512, 0, stream>>>(qkvp, ck, cv, pos, attnout);
  // wo: K-split x4, whole-x-in-LDS (32 KB each), deterministic sum after
  gemv_xlds<4><<<4 * 128, 512, 32768, stream>>>(wo, wo, wo, attnout, wopart,
                                                128, 128, B_ * HID_);
  sum4<<<(B_ * HID_) / (256 * 4), 256, 0, stream>>>(wopart, out);
}

// Round 18
// 158.760 us; speedup vs baseline: 1.3751x; 1.3751x over previous
//
#include <hip/hip_runtime.h>
#include <cmath>
#include <cstdint>

// Problem constants (fixed by reference file)
#define B_     8
#define NH_    32
#define HD_    128
#define HID_   4096
#define MAXS_  4096
#define NPAIR_ (B_ * NH_)          // 256 (b,h) pairs
#define QS_    (3 * B_ * HID_)     // qkv partial stride (one K-half)
#define NEG_BIG_ (-1e30f)

typedef float f4_ __attribute__((ext_vector_type(4)));

__device__ __forceinline__ f4_ ntload4(const float* p) {
  return __builtin_nontemporal_load((const f4_*)p);
}
__device__ __forceinline__ f4_ ld4(const float* p) {
  return *(const f4_*)p;
}
__device__ __forceinline__ float dot4(f4_ a, f4_ b) {
  f4_ m = a * b;
  return m.x + m.y + m.z + m.w;
}

// Async global->LDS stage of 16 B/lane (1 KB per wave-instruction).
// Per-lane global src; LDS dest = wave-uniform byte offset + lane*16.
// Dynamic-LDS raw offsets (no static __shared__). Verified in round 9.
__device__ __forceinline__ void stage16(const float* gsrc, unsigned ldsoff) {
  __builtin_amdgcn_global_load_lds(
      (__attribute__((address_space(1))) void*)(uintptr_t)gsrc,
      (__attribute__((address_space(3))) void*)ldsoff,
      16, 0, 0);
}

// Pure-weight-stream GEMV (round-16 empirical best, 167.4 us): 4-wave block,
// 32 rows (8/wave), NSL K-slices of 256. Whole x K-range staged to LDS once
// (one barrier); stream loop = reg-double-buffered weight loads + ds_read x
// + FMA only. Round-17 lesson: do NOT constrain VGPR via __launch_bounds__
// min-waves — the 128-VGPR budget spills/serializes the load pipeline, and
// TLP cannot raise in-flight weight bytes anyway (16w x 4KB == 8w x 8KB).
// Weights NORMAL loads (L3-resident across graph replays; the nt KV stream
// can't evict them — round-5/6 A/B, worth ~32 us).
template<int NSL>
__global__ __launch_bounds__(256) void gemv_xlds(
    const float* __restrict__ W0, const float* __restrict__ W1,
    const float* __restrict__ W2, const float* __restrict__ x,
    float* __restrict__ out, int nb_per_mat, int n_inner, int part_stride)
{
  extern __shared__ float dyn[];            // [8][NSL][256] floats
  const int bid   = blockIdx.x;
  const int ks    = bid / n_inner;          // K-split index
  const int inner = bid % n_inner;
  const int m     = inner / nb_per_mat;     // matrix index (0..2)
  const int r0    = (inner % nb_per_mat) * 32;
  const float* __restrict__ W = (m == 0) ? W0 : ((m == 1) ? W1 : W2);
  float* o = out + (size_t)ks * part_stride + m * (B_ * HID_);

  const int wib  = threadIdx.x >> 6;
  const int lane = threadIdx.x & 63;
  const int kofs = ks * NSL * 256;
  const int rw   = r0 + wib * 8;            // wave's first row

  float acc[8][8];
#pragma unroll
  for (int r = 0; r < 8; ++r)
#pragma unroll
    for (int b = 0; b < 8; ++b) acc[r][b] = 0.f;

  const float* Wp = W + (size_t)rw * HID_ + kofs + lane * 4;
  const float* xp = x + kofs + lane * 4;

  // stage the whole x K-range: wave wib stages batches {2wib, 2wib+1}
#pragma unroll
  for (int bb = 0; bb < 2; ++bb) {
    const int b = 2 * wib + bb;
#pragma unroll
    for (int s = 0; s < NSL; ++s)
      stage16(xp + (size_t)b * HID_ + s * 256,
              (unsigned)((b * NSL + s) * 1024));
  }

  f4_ wa[8], wb[8];
#pragma unroll
  for (int r = 0; r < 8; ++r) wa[r] = ld4(Wp + (size_t)r * HID_);
  __syncthreads();                          // one-time drain; staging done

#define COMP_(BUF, u)                                                         \
  {                                                                           \
    f4_ xv[8];                                                                \
    _Pragma("unroll")                                                         \
    for (int b = 0; b < 8; ++b)                                               \
      xv[b] = ld4(&dyn[(b * NSL + (u)) * 256 + lane * 4]);                    \
    _Pragma("unroll")                                                         \
    for (int r = 0; r < 8; ++r)                                               \
      _Pragma("unroll")                                                       \
      for (int b = 0; b < 8; ++b) acc[r][b] += dot4(BUF[r], xv[b]);           \
  }

#pragma unroll 1
  for (int u = 0; u < NSL; u += 2) {
    {
#pragma unroll
      for (int r = 0; r < 8; ++r)
        wb[r] = ld4(Wp + (size_t)r * HID_ + (u + 1) * 256);
      COMP_(wa, u);
    }
    {
      if (u + 2 < NSL) {
#pragma unroll
        for (int r = 0; r < 8; ++r)
          wa[r] = ld4(Wp + (size_t)r * HID_ + (u + 2) * 256);
      }
      COMP_(wb, u + 1);
    }
  }
#undef COMP_

  // butterfly reduce each of the 64 partials across the wave
#pragma unroll
  for (int r = 0; r < 8; ++r)
#pragma unroll
    for (int b = 0; b < 8; ++b) {
      float v = acc[r][b];
#pragma unroll
      for (int off = 32; off; off >>= 1) v += __shfl_xor(v, off);
      acc[r][b] = v;
    }

  if (lane == 0) {
#pragma unroll
    for (int r = 0; r < 8; ++r)
#pragma unroll
      for (int b = 0; b < 8; ++b)
        o[(size_t)b * HID_ + rw + r] = acc[r][b];
  }
}

// out[i] = sum of 4 K-split partials (deterministic, no atomics).
__global__ __launch_bounds__(256) void sum4(
    const float* __restrict__ part, float* __restrict__ out)
{
  const int gid = blockIdx.x * 256 + threadIdx.x;   // 8192 f4 elements
  const int i = gid * 4;
  f4_ v = ld4(part + i) + ld4(part + (B_ * HID_) + i)
        + ld4(part + 2 * (B_ * HID_) + i) + ld4(part + 3 * (B_ * HID_) + i);
  *(f4_*)(out + i) = v;
}

// Fused flash-decoding attention: ONE block (512 thr = 8 waves) per (b,h),
// combine in-block. q/k/v-fresh are the SUM of the two QKV K-split halves.
// K/V rows nt (stream-once; must not evict L3-resident weights).
__global__ __launch_bounds__(512) void attn_pair(
    const float* __restrict__ qkv, const float* __restrict__ ck,
    const float* __restrict__ cv, const int* __restrict__ ppos,
    float* __restrict__ attnout)
{
  __shared__ float sm[8], sl[8];
  __shared__ float sacc[8][HD_];

  const int pos  = *ppos;
  const int pair = blockIdx.x;
  const int b    = pair >> 5;
  const int h    = pair & (NH_ - 1);
  const int w    = threadIdx.x >> 6;
  const int lane = threadIdx.x & 63;
  const int half = lane >> 5, l32 = lane & 31;
  const int k0   = w * 256;

  float m = NEG_BIG_, l = 0.f;
  f4_ acc = (f4_)0.f;

  if (k0 <= pos) {
    const float scale = 0.08838834764831845f;   // 1/sqrt(128)
    const int hoff = b * HID_ + h * HD_ + l32 * 4;
    f4_ q4  = (ld4(qkv + hoff) + ld4(qkv + QS_ + hoff)) * scale;
    f4_ kf4 =  ld4(qkv + B_ * HID_ + hoff) + ld4(qkv + QS_ + B_ * HID_ + hoff);
    f4_ vf4 =  ld4(qkv + 2 * B_ * HID_ + hoff) + ld4(qkv + QS_ + 2 * B_ * HID_ + hoff);
    const float* ckh = ck + ((size_t)(b * NH_ + h)) * MAXS_ * HD_;
    const float* cvh = cv + ((size_t)(b * NH_ + h)) * MAXS_ * HD_;

    for (int c = 0; c < 16; ++c) {
      const int kbase = k0 + c * 16;
      f4_ k4[8], v4[8];
#pragma unroll
      for (int j = 0; j < 8; ++j) {
        const int ki = kbase + 2 * j + half;
        k4[j] = ntload4(ckh + (size_t)ki * HD_ + l32 * 4);
        v4[j] = ntload4(cvh + (size_t)ki * HD_ + l32 * 4);
      }
      // fresh-token overwrite (ki==pos row of the cache is stale)
#pragma unroll
      for (int j = 0; j < 8; ++j) {
        const int ki = kbase + 2 * j + half;
        if (ki == pos) { k4[j] = kf4; v4[j] = vf4; }
      }

      float sc[8];
#pragma unroll
      for (int j = 0; j < 8; ++j) sc[j] = dot4(q4, k4[j]);

#pragma unroll
      for (int off = 16; off >= 1; off >>= 1)
#pragma unroll
        for (int j = 0; j < 8; ++j) sc[j] += __shfl_xor(sc[j], off);

#pragma unroll
      for (int j = 0; j < 8; ++j) {
        const int ki = kbase + 2 * j + half;
        if (ki > pos) sc[j] = -INFINITY;
      }

      const float cm = fmaxf(fmaxf(fmaxf(sc[0], sc[1]), fmaxf(sc[2], sc[3])),
                             fmaxf(fmaxf(sc[4], sc[5]), fmaxf(sc[6], sc[7])));
      const float mn   = fmaxf(m, cm);
      const float corr = __expf(m - mn);
      float p[8], ps = 0.f;
#pragma unroll
      for (int j = 0; j < 8; ++j) { p[j] = __expf(sc[j] - mn); ps += p[j]; }
      l = l * corr + ps;
      acc *= corr;
#pragma unroll
      for (int j = 0; j < 8; ++j) acc += p[j] * v4[j];
      m = mn;
    }
  }

  // merge the two halves of each wave
  const float mo = __shfl_xor(m, 32);
  const float lo = __shfl_xor(l, 32);
  f4_ ao;
  ao.x = __shfl_xor(acc.x, 32); ao.y = __shfl_xor(acc.y, 32);
  ao.z = __shfl_xor(acc.z, 32); ao.w = __shfl_xor(acc.w, 32);
  const float mm = fmaxf(m, mo);
  const float w0 = __expf(m - mm), w1 = __expf(mo - mm);
  const float lm = l * w0 + lo * w1;
  f4_ am = acc * w0 + ao * w1;

  if (half == 0) {
    *(f4_*)&sacc[w][l32 * 4] = am;
    if (l32 == 0) { sm[w] = mm; sl[w] = lm; }
  }
  __syncthreads();

  // final merge of the 8 wave-partials (32 threads, one f4 per thread)
  if (threadIdx.x < 32) {
    const int t = threadIdx.x;
    float mg = NEG_BIG_;
#pragma unroll
    for (int u = 0; u < 8; ++u)
      if (sl[u] > 0.f) mg = fmaxf(mg, sm[u]);
    float ls = 0.f;
    f4_ o = (f4_)0.f;
#pragma unroll
    for (int u = 0; u < 8; ++u)
      if (sl[u] > 0.f) {
        const float wu = __expf(sm[u] - mg);
        ls += sl[u] * wu;
        o  += wu * ld4(&sacc[u][t * 4]);
      }
    *(f4_*)(attnout + pair * HD_ + t * 4) = o / ls;
  }
}

extern "C" void kernel_launch(void* const* d_in, const int* in_sizes, int n_in,
                              void* d_out, int out_size, void* d_ws, size_t ws_size,
                              hipStream_t stream) {
  const float* x  = (const float*)d_in[0];
  const float* ck = (const float*)d_in[1];
  const float* cv = (const float*)d_in[2];
  const float* wq = (const float*)d_in[3];
  const float* wk = (const float*)d_in[4];
  const float* wv = (const float*)d_in[5];
  const float* wo = (const float*)d_in[6];
  const int* pos  = (const int*)d_in[7];
  float* out = (float*)d_out;
  float* ws  = (float*)d_ws;

  float* qkvp    = ws;                                   // 2 * QS_ floats
  float* attnout = qkvp + 2 * QS_;                       // B*HID
  float* wopart  = attnout + B_ * HID_;                  // 4 * B*HID

  // QKV: K-split x2, 32-row 4-wave blocks, whole-x-in-LDS (64 KB each)
  gemv_xlds<8><<<2 * 3 * 128, 256, 65536, stream>>>(wq, wk, wv, x, qkvp,
                                                    128, 3 * 128, QS_);
  // attention + combine fused (sums the two qkv K-halves on load)
  attn_pair<<<NPAIR_, 512, 0, stream>>>(qkvp, ck, cv, pos, attnout);
  // wo: K-split x4, whole-x-in-LDS (32 KB each), deterministic sum after
  gemv_xlds<4><<<4 * 128, 256, 32768, stream>>>(wo, wo, wo, attnout, wopart,
                                                128, 128, B_ * HID_);
  sum4<<<(B_ * HID_) / (256 * 4), 256, 0, stream>>>(wopart, out);
}